// Round 10
// baseline (227.762 us; speedup 1.0000x reference)
//
#include <hip/hip_runtime.h>
#include <hip/hip_bf16.h>
#include <cstdint>
#include <cstddef>

#define B_ 16
#define N_ 2048
#define L_ 12
#define C_ 32
#define KTOP 1638
#define SCALE 0.17677669529663687f   // 1/sqrt(32)
#define LOG2E 1.44269504088896f
#define TS 8                          // t-iterations per wave (16 waves x 128 cols)

typedef __attribute__((ext_vector_type(8))) short short8v;
typedef __attribute__((ext_vector_type(4))) float f32x4;

#if __has_builtin(__builtin_amdgcn_exp2f)
#define EXP2F(x) __builtin_amdgcn_exp2f(x)
#else
#define EXP2F(x) exp2f(x)
#endif

__device__ __forceinline__ unsigned short bf16_rne(float v) {
  unsigned u = __float_as_uint(v);
  u += 0x7FFFu + ((u >> 16) & 1u);
  return (unsigned short)(u >> 16);
}
__device__ __forceinline__ unsigned key15(unsigned short b16) {
  const unsigned s = b16 >> 15;
  return ((((unsigned)b16) ^ 0x8000u ^ (s * 0x7FFFu)) >> 1) & 0x7FFFu;
}

// Kernel 1: xsum split into bf16 hi/lo, layout [b][n][c]; blocks with b==0
// also convert mem (f32 [c][m]) -> bf16 memT [m][c] (batch-invariant).
__global__ __launch_bounds__(256) void prep_kernel(const float* __restrict__ x,
                                                   const float* __restrict__ mem,
                                                   unsigned short* __restrict__ xsH,
                                                   unsigned short* __restrict__ xsL,
                                                   unsigned short* __restrict__ memT) {
  const int b = blockIdx.y, n0 = blockIdx.x * 64;
  const int c = threadIdx.x & 31, nr = threadIdx.x >> 5;
#pragma unroll
  for (int i = 0; i < 8; ++i) {
    const int n = n0 + i * 8 + nr;
    const float* px = x + ((size_t)(b * N_ + n) * L_) * C_ + c;
    float s = 0.f;
#pragma unroll
    for (int l = 0; l < L_; ++l) s += px[l * C_];
    const unsigned short h = bf16_rne(s);
    const float hf = __uint_as_float((unsigned)h << 16);
    const unsigned short lo = bf16_rne(s - hf);
    const size_t o = (size_t)(b * N_ + n) * C_ + c;
    xsH[o] = h;
    xsL[o] = lo;
  }
  if (b == 0) {
#pragma unroll
    for (int i = 0; i < 8; ++i) {
      const int idx = i * 256 + threadIdx.x;
      const int ml = idx >> 5, cc = idx & 31;
      memT[(size_t)(n0 + ml) * C_ + cc] = bf16_rne(mem[(size_t)cc * N_ + n0 + ml]);
    }
  }
}

// Kernel 2: one block = 8 rows x 2048 cols, 1024 threads (16 waves, 128 cols
// each). Phase A: MFMA 16x16x32, permuted A-row padding; p1/p2 kept packed in
// REGISTERS (no 64KB staging). All cross-wave aggregation via group-shfl +
// ~2KB LDS partials. Tie-anchored fast-path threshold (self-verifying);
// rare block-uniform binary-search fallback.
__global__ __launch_bounds__(1024) void adj_kernel(
    const unsigned short* __restrict__ xsH, const unsigned short* __restrict__ xsL,
    const unsigned short* __restrict__ memT, const float* __restrict__ fc_w,
    const float* __restrict__ fc_b, float* __restrict__ out) {
  __shared__ float redS1[8][16], redS2[8][16];   // [row][wave]
  __shared__ unsigned redC[2][4][16];            // [ge/gt][group][wave], packed row-pair
  __shared__ float redE[8][16];                  // final exp sums

  const int tid = threadIdx.x, wid = tid >> 6, lane = tid & 63;
  const int l15 = lane & 15, g = lane >> 4;
  const int b = blockIdx.y, n0 = blockIdx.x * 8;

  // Permuted A rows: lane group g's C components {0,1} are logical rows
  // {rbase, rbase+1}, rbase = {0,4,2,6}[g].
  const int fr = (l15 < 8) ? l15 : ((l15 - 6) & 7);
  const int rbase = (g & 1) * 4 + (g & 2);
  const int g8 = g * 8;
  const size_t arow = (size_t)(b * N_ + n0 + fr) * C_ + g8;
  const short8v hiA = *(const short8v*)(xsH + arow);
  const short8v loFA = *(const short8v*)(xsL + arow);

  const f32x4 zero = {0.f, 0.f, 0.f, 0.f};
  const float K = SCALE * LOG2E;
  const float C2 = -80.f * LOG2E;
  const int mbase = wid * 128 + l15;
  const size_t bcol = (size_t)b * N_ * C_ + (size_t)mbase * C_ + g8;
  const unsigned short* pH = xsH + bcol;
  const unsigned short* pL = xsL + bcol;
  const unsigned short* pM = memT + (size_t)mbase * C_ + g8;

  float s1[2] = {0.f, 0.f}, s2[2] = {0.f, 0.f};
  unsigned pA[TS], pB[TS];

#pragma unroll
  for (int t = 0; t < TS; ++t) {
    const short8v hiB = *(const short8v*)(pH + t * (16 * C_));
    const short8v loB = *(const short8v*)(pL + t * (16 * C_));
    const short8v mB  = *(const short8v*)(pM + t * (16 * C_));

    f32x4 acc1 = __builtin_amdgcn_mfma_f32_16x16x32_bf16(hiA, mB, zero, 0, 0, 0);
    f32x4 acc2 = __builtin_amdgcn_mfma_f32_16x16x32_bf16(hiA, hiB, zero, 0, 0, 0);
    acc2 = __builtin_amdgcn_mfma_f32_16x16x32_bf16(hiA, loB, acc2, 0, 0, 0);
    acc2 = __builtin_amdgcn_mfma_f32_16x16x32_bf16(loFA, hiB, acc2, 0, 0, 0);

    {
      const float p1 = EXP2F(fmaxf(acc1[0], 0.f) * K);
      const float p2 = EXP2F(fminf(fmaf(fmaxf(acc2[0], 0.f), K, C2), 127.f));
      s1[0] += p1; s2[0] += p2;
      union { __hip_bfloat162 h2; unsigned u; } pk;
      pk.h2 = __float22bfloat162_rn(float2{p1, p2});
      pA[t] = pk.u;
    }
    {
      const float p1 = EXP2F(fmaxf(acc1[1], 0.f) * K);
      const float p2 = EXP2F(fminf(fmaf(fmaxf(acc2[1], 0.f), K, C2), 127.f));
      s1[1] += p1; s2[1] += p2;
      union { __hip_bfloat162 h2; unsigned u; } pk;
      pk.h2 = __float22bfloat162_rn(float2{p1, p2});
      pB[t] = pk.u;
    }
  }

  // ---- S1/S2: group-shfl reduce (16 lanes = 16 cols) + block reduce ----
#pragma unroll
  for (int d = 1; d < 16; d <<= 1) {
#pragma unroll
    for (int s = 0; s < 2; ++s) {
      s1[s] += __shfl_xor(s1[s], d);
      s2[s] += __shfl_xor(s2[s], d);
    }
  }
  if (l15 == 0) {
    redS1[rbase][wid] = s1[0]; redS1[rbase + 1][wid] = s1[1];
    redS2[rbase][wid] = s2[0]; redS2[rbase + 1][wid] = s2[1];
  }
  __syncthreads();
  float S1A = 0.f, S1B = 0.f, S2A = 0.f, S2B = 0.f;
#pragma unroll
  for (int w = 0; w < 16; ++w) {
    S1A += redS1[rbase][w]; S1B += redS1[rbase + 1][w];
    S2A += redS2[rbase][w]; S2B += redS2[rbase + 1][w];
  }
  const float w0 = fc_w[0], w1 = fc_w[1], bb = fc_b[0];
  const float i1A = w0 / S1A, i2A = w1 / S2A;
  const float i1B = w0 / S1B, i2B = w1 / S2B;

  // ---- adj + packed keys (rows A/B in u32 halves) ----
  unsigned kg[TS], mk[TS];
#pragma unroll
  for (int t = 0; t < TS; ++t) {
    const unsigned qa = pA[t], qb = pB[t];
    const float adjA = fmaf(__uint_as_float(qa & 0xFFFF0000u), i2A,
                      fmaf(__uint_as_float(qa << 16), i1A, bb));
    const float adjB = fmaf(__uint_as_float(qb & 0xFFFF0000u), i2B,
                      fmaf(__uint_as_float(qb << 16), i1B, bb));
    union { __hip_bfloat162 h2; unsigned u; } c;
    c.h2 = __float22bfloat162_rn(float2{adjA, adjB});
    mk[t] = c.u;
    const unsigned sgn = (c.u >> 15) & 0x00010001u;
    const unsigned srt = c.u ^ 0x80008000u ^ (sgn * 0x7FFFu);
    kg[t] = ((srt >> 1) & 0x7FFF7FFFu) | 0x80008000u;
  }

  // ---- tie-anchor thresholds (per row) + fast-path counts ----
  const float p2t = __uint_as_float((unsigned)bf16_rne(EXP2F(C2)) << 16);
  const unsigned kTA = key15(bf16_rne(fmaf(p2t, i2A, fmaf(1.0f, i1A, bb))));
  const unsigned kTB = key15(bf16_rne(fmaf(p2t, i2B, fmaf(1.0f, i1B, bb))));
  const unsigned mmA = kTA | (kTB << 16);
  const unsigned mmB = (kTA + 1u) | ((kTB + 1u) << 16);
  unsigned cge = 0, cgt = 0;
#pragma unroll
  for (int t = 0; t < TS; ++t) {
    cge += ((kg[t] - mmA) >> 15) & 0x10001u;
    cgt += ((kg[t] - mmB) >> 15) & 0x10001u;
  }
#pragma unroll
  for (int d = 1; d < 16; d <<= 1) {
    cge += (unsigned)__shfl_xor((int)cge, d);
    cgt += (unsigned)__shfl_xor((int)cgt, d);
  }
  if (l15 == 0) { redC[0][g][wid] = cge; redC[1][g][wid] = cgt; }
  __syncthreads();
  unsigned CGE = 0, CGT = 0;
#pragma unroll
  for (int w = 0; w < 16; ++w) { CGE += redC[0][g][w]; CGT += redC[1][g][w]; }
  const unsigned cgeA = CGE & 0xFFFFu, cgeB = CGE >> 16;
  const unsigned cgtA = CGT & 0xFFFFu, cgtB = CGT >> 16;
  const bool okA = (cgeA >= KTOP) && (cgtA < KTOP);
  const bool okB = (cgeB >= KTOP) && (cgtB < KTOP);
  unsigned thrA = kTA, thrB = kTB;

  if (!__all(okA && okB)) {
    // ---- rare fallback: block-uniform packed binary search for all rows ----
    __syncthreads();  // protect redC reuse
    unsigned mnA = 0x7FFFu, mxA = 0u, mnB = 0x7FFFu, mxB = 0u;
#pragma unroll
    for (int t = 0; t < TS; ++t) {
      const unsigned kA = kg[t] & 0x7FFFu, kB = (kg[t] >> 16) & 0x7FFFu;
      mnA = min(mnA, kA); mxA = max(mxA, kA);
      mnB = min(mnB, kB); mxB = max(mxB, kB);
    }
#pragma unroll
    for (int d = 1; d < 16; d <<= 1) {
      mnA = min(mnA, (unsigned)__shfl_xor((int)mnA, d));
      mxA = max(mxA, (unsigned)__shfl_xor((int)mxA, d));
      mnB = min(mnB, (unsigned)__shfl_xor((int)mnB, d));
      mxB = max(mxB, (unsigned)__shfl_xor((int)mxB, d));
    }
    if (l15 == 0) {
      redC[0][g][wid] = mnA | (mnB << 16);
      redC[1][g][wid] = mxA | (mxB << 16);
    }
    __syncthreads();
    mnA = 0x7FFFu; mxA = 0u; mnB = 0x7FFFu; mxB = 0u;
#pragma unroll
    for (int w = 0; w < 16; ++w) {
      const unsigned vn = redC[0][g][w], vx = redC[1][g][w];
      mnA = min(mnA, vn & 0xFFFFu); mnB = min(mnB, vn >> 16);
      mxA = max(mxA, vx & 0xFFFFu); mxB = max(mxB, vx >> 16);
    }
    unsigned lA = mnA, hA = mxA, lB = mnB, hB = mxB;
#pragma unroll 1
    for (int it = 0; it < 15; ++it) {
      const unsigned midA = (lA + hA + 1u) >> 1;
      const unsigned midB = (lB + hB + 1u) >> 1;
      const unsigned mm = midA | (midB << 16);
      unsigned cnt = 0;
#pragma unroll
      for (int t = 0; t < TS; ++t) cnt += ((kg[t] - mm) >> 15) & 0x10001u;
#pragma unroll
      for (int d = 1; d < 16; d <<= 1) cnt += (unsigned)__shfl_xor((int)cnt, d);
      __syncthreads();
      if (l15 == 0) redC[0][g][wid] = cnt;
      __syncthreads();
      unsigned CNT = 0;
#pragma unroll
      for (int w = 0; w < 16; ++w) CNT += redC[0][g][w];
      const unsigned cA = CNT & 0xFFFFu, cB = CNT >> 16;
      if (cA >= KTOP) lA = midA; else hA = midA - 1u;
      if (cB >= KTOP) lB = midB; else hB = midB - 1u;
    }
    thrA = lA; thrB = lB;
  }

  // ---- mask + exp-sum ----
  const unsigned lolo = thrA | (thrB << 16);
  float sA = 0.f, sB = 0.f;
#pragma unroll
  for (int t = 0; t < TS; ++t) {
    const unsigned ge = kg[t] - lolo;
    const unsigned msk = ((ge & 0x8000u) ? 0xFFFFu : 0u) |
                         ((ge & 0x80000000u) ? 0xFFFF0000u : 0u);
    mk[t] &= msk;
    sA += EXP2F(__uint_as_float(mk[t] << 16) * LOG2E);
    sB += EXP2F(__uint_as_float(mk[t] & 0xFFFF0000u) * LOG2E);
  }
#pragma unroll
  for (int d = 1; d < 16; d <<= 1) {
    sA += __shfl_xor(sA, d);
    sB += __shfl_xor(sB, d);
  }
  if (l15 == 0) { redE[rbase][wid] = sA; redE[rbase + 1][wid] = sB; }
  __syncthreads();
  float SEA = 0.f, SEB = 0.f;
#pragma unroll
  for (int w = 0; w < 16; ++w) { SEA += redE[rbase][w]; SEB += redE[rbase + 1][w]; }
  const float invA = 1.f / SEA, invB = 1.f / SEB;

  // ---- store (recompute exp; masked entries are exp(0)=1) ----
  float* opA = out + ((size_t)(b * N_ + n0 + rbase)) * N_ + mbase;
  float* opB = opA + N_;
#pragma unroll
  for (int t = 0; t < TS; ++t) {
    opA[t * 16] = EXP2F(__uint_as_float(mk[t] << 16) * LOG2E) * invA;
    opB[t * 16] = EXP2F(__uint_as_float(mk[t] & 0xFFFF0000u) * LOG2E) * invB;
  }
}

extern "C" void kernel_launch(void* const* d_in, const int* in_sizes, int n_in,
                              void* d_out, int out_size, void* d_ws, size_t ws_size,
                              hipStream_t stream) {
  const float* x   = (const float*)d_in[0];
  const float* mem = (const float*)d_in[1];
  const float* fcw = (const float*)d_in[2];
  const float* fcb = (const float*)d_in[3];
  float* out = (float*)d_out;
  unsigned short* xsH  = (unsigned short*)d_ws;             // 2 MB
  unsigned short* xsL  = xsH + (size_t)B_ * N_ * C_;        // 2 MB
  unsigned short* memT = xsL + (size_t)B_ * N_ * C_;        // 128 KB

  dim3 g1(N_ / 64, B_);
  prep_kernel<<<g1, 256, 0, stream>>>(x, mem, xsH, xsL, memT);
  dim3 g2(N_ / 8, B_);
  adj_kernel<<<g2, 1024, 0, stream>>>(xsH, xsL, memT, fcw, fcb, out);
}

// Round 11
// 161.617 us; speedup vs baseline: 1.4093x; 1.4093x over previous
//
#include <hip/hip_runtime.h>
#include <hip/hip_bf16.h>
#include <cstdint>
#include <cstddef>

#define B_ 16
#define N_ 2048
#define L_ 12
#define C_ 32
#define KTOP 1638
#define SCALE 0.17677669529663687f   // 1/sqrt(32)
#define LOG2E 1.44269504088896f

typedef __attribute__((ext_vector_type(8))) short short8v;
typedef __attribute__((ext_vector_type(4))) float f32x4;

#if __has_builtin(__builtin_amdgcn_exp2f)
#define EXP2F(x) __builtin_amdgcn_exp2f(x)
#else
#define EXP2F(x) exp2f(x)
#endif

__device__ __forceinline__ unsigned short bf16_rne(float v) {
  unsigned u = __float_as_uint(v);
  u += 0x7FFFu + ((u >> 16) & 1u);
  return (unsigned short)(u >> 16);
}
__device__ __forceinline__ unsigned key15(unsigned short b16) {
  const unsigned s = b16 >> 15;
  return ((((unsigned)b16) ^ 0x8000u ^ (s * 0x7FFFu)) >> 1) & 0x7FFFu;
}

// Kernel 1: xsum split into bf16 hi/lo, layout [b][n][c]; blocks with b==0
// also convert mem (f32 [c][m]) -> bf16 memT [m][c] (batch-invariant).
__global__ __launch_bounds__(256) void prep_kernel(const float* __restrict__ x,
                                                   const float* __restrict__ mem,
                                                   unsigned short* __restrict__ xsH,
                                                   unsigned short* __restrict__ xsL,
                                                   unsigned short* __restrict__ memT) {
  const int b = blockIdx.y, n0 = blockIdx.x * 64;
  const int c = threadIdx.x & 31, nr = threadIdx.x >> 5;
#pragma unroll
  for (int i = 0; i < 8; ++i) {
    const int n = n0 + i * 8 + nr;
    const float* px = x + ((size_t)(b * N_ + n) * L_) * C_ + c;
    float s = 0.f;
#pragma unroll
    for (int l = 0; l < L_; ++l) s += px[l * C_];
    const unsigned short h = bf16_rne(s);
    const float hf = __uint_as_float((unsigned)h << 16);
    const unsigned short lo = bf16_rne(s - hf);
    const size_t o = (size_t)(b * N_ + n) * C_ + c;
    xsH[o] = h;
    xsL[o] = lo;
  }
  if (b == 0) {
#pragma unroll
    for (int i = 0; i < 8; ++i) {
      const int idx = i * 256 + threadIdx.x;
      const int ml = idx >> 5, cc = idx & 31;
      memT[(size_t)(n0 + ml) * C_ + cc] = bf16_rne(mem[(size_t)cc * N_ + n0 + ml]);
    }
  }
}

// Kernel 2: one block = 8 rows of one batch, 512 threads (8 waves), R8 skeleton.
// Staging: p1 as u8 fixed-point (1+q/128, 16.6KB) + p2 as bf16 u16 (33KB)
// -> ~49KB LDS -> 3 blocks/CU; launch_bounds(512,6) caps VGPR at 42 for
// 6 waves/SIMD. Phase B: reconstruct -> packed 15-bit keys -> tie-anchored
// fast-path threshold -> POLY-exp (cubic, ballot fixup for |adj|>0.25) ->
// float4 coalesced stores (lane-consecutive column ownership).
__global__ __launch_bounds__(512, 6) void adj_kernel(
    const unsigned short* __restrict__ xsH, const unsigned short* __restrict__ xsL,
    const unsigned short* __restrict__ memT, const float* __restrict__ fc_w,
    const float* __restrict__ fc_b, float* __restrict__ out) {
  __shared__ unsigned char  p1b[8][2080];    // pad 32B: conflict-spread rows
  __shared__ unsigned short p2b[8][2064];    // pad 16 u16
  __shared__ float red1[8][8], red2[8][8];

  const int tid = threadIdx.x, wid = tid >> 6, lane = tid & 63;
  const int l15 = lane & 15, g = lane >> 4;
  const int b = blockIdx.y, n0 = blockIdx.x * 8;

  // Permuted A rows: lane group g's C components {0,1} are logical rows
  // {rbase, rbase+1}, rbase = {0,4,2,6}[g].
  const int fr = (l15 < 8) ? l15 : ((l15 - 6) & 7);
  const int rbase = (g & 1) * 4 + (g & 2);
  const int g8 = g * 8;
  const size_t arow = (size_t)(b * N_ + n0 + fr) * C_ + g8;
  const short8v hiA = *(const short8v*)(xsH + arow);
  const short8v loFA = *(const short8v*)(xsL + arow);

  const f32x4 zero = {0.f, 0.f, 0.f, 0.f};
  const float K = SCALE * LOG2E;
  const float C2 = -80.f * LOG2E;
  const int mbase = wid * 256 + l15;
  const size_t bcol = (size_t)b * N_ * C_ + (size_t)mbase * C_ + g8;
  const unsigned short* pH = xsH + bcol;
  const unsigned short* pL = xsL + bcol;
  const unsigned short* pM = memT + (size_t)mbase * C_ + g8;

  float s1[2] = {0.f, 0.f}, s2[2] = {0.f, 0.f};

#pragma unroll 2
  for (int t = 0; t < 16; ++t) {
    const short8v hiB = *(const short8v*)(pH + t * (16 * C_));
    const short8v loB = *(const short8v*)(pL + t * (16 * C_));
    const short8v mB  = *(const short8v*)(pM + t * (16 * C_));

    f32x4 acc1 = __builtin_amdgcn_mfma_f32_16x16x32_bf16(hiA, mB, zero, 0, 0, 0);
    f32x4 acc2 = __builtin_amdgcn_mfma_f32_16x16x32_bf16(hiA, hiB, zero, 0, 0, 0);
    acc2 = __builtin_amdgcn_mfma_f32_16x16x32_bf16(hiA, loB, acc2, 0, 0, 0);
    acc2 = __builtin_amdgcn_mfma_f32_16x16x32_bf16(loFA, hiB, acc2, 0, 0, 0);

    const int m = mbase + t * 16;
#pragma unroll
    for (int s = 0; s < 2; ++s) {
      const float p1 = EXP2F(fmaxf(acc1[s], 0.f) * K);
      const float p2 = EXP2F(fminf(fmaf(fmaxf(acc2[s], 0.f), K, C2), 127.f));
      s1[s] += p1; s2[s] += p2;
      // q = round((p1-1)*128); p1==1 (tie class) -> q==0 exactly
      p1b[rbase + s][m] = (unsigned char)fminf(fmaf(p1, 128.f, -127.5f), 255.f);
      p2b[rbase + s][m] = bf16_rne(p2);
    }
  }

#pragma unroll
  for (int d = 1; d < 16; d <<= 1) {
#pragma unroll
    for (int s = 0; s < 2; ++s) {
      s1[s] += __shfl_xor(s1[s], d);
      s2[s] += __shfl_xor(s2[s], d);
    }
  }
  if (l15 == 0) {
#pragma unroll
    for (int s = 0; s < 2; ++s) {
      red1[wid][rbase + s] = s1[s];
      red2[wid][rbase + s] = s2[s];
    }
  }
  __syncthreads();

  // ---- Phase B: wave wid owns row wid; lane owns cols {4*lane+256k} ----
  const int r = wid;
  float S1 = 0.f, S2 = 0.f;
#pragma unroll
  for (int w = 0; w < 8; ++w) { S1 += red1[w][r]; S2 += red2[w][r]; }
  const float w0 = fc_w[0], w1 = fc_w[1], bb = fc_b[0];
  const float i1 = w0 / S1, i2 = w1 / S2;

  unsigned pk[16], kg[16];
  const unsigned char*  pr1 = &p1b[r][0];
  const unsigned short* pr2 = &p2b[r][0];
#pragma unroll
  for (int k = 0; k < 8; ++k) {
    const int c0 = 4 * lane + 256 * k;
    const unsigned q8 = *(const unsigned*)(pr1 + c0);
    const ushort4 q16 = *(const ushort4*)(pr2 + c0);
    const float a0 = fmaf(__uint_as_float((unsigned)q16.x << 16), i2,
                    fmaf(fmaf((float)(unsigned char)(q8      ), 0.0078125f, 1.f), i1, bb));
    const float a1 = fmaf(__uint_as_float((unsigned)q16.y << 16), i2,
                    fmaf(fmaf((float)(unsigned char)(q8 >>  8), 0.0078125f, 1.f), i1, bb));
    const float a2 = fmaf(__uint_as_float((unsigned)q16.z << 16), i2,
                    fmaf(fmaf((float)(unsigned char)(q8 >> 16), 0.0078125f, 1.f), i1, bb));
    const float a3 = fmaf(__uint_as_float((unsigned)q16.w << 16), i2,
                    fmaf(fmaf((float)(unsigned char)(q8 >> 24), 0.0078125f, 1.f), i1, bb));
    union { __hip_bfloat162 h2; unsigned u; } cA, cB;
    cA.h2 = __float22bfloat162_rn(float2{a0, a1});
    cB.h2 = __float22bfloat162_rn(float2{a2, a3});
    pk[2 * k] = cA.u; pk[2 * k + 1] = cB.u;
    unsigned sgn = (cA.u >> 15) & 0x00010001u;
    unsigned srt = cA.u ^ 0x80008000u ^ (sgn * 0x7FFFu);
    kg[2 * k] = ((srt >> 1) & 0x7FFF7FFFu) | 0x80008000u;
    sgn = (cB.u >> 15) & 0x00010001u;
    srt = cB.u ^ 0x80008000u ^ (sgn * 0x7FFFu);
    kg[2 * k + 1] = ((srt >> 1) & 0x7FFF7FFFu) | 0x80008000u;
  }

  // ---- tie-anchored threshold (self-verifying fast path) ----
  const float p2t = __uint_as_float((unsigned)bf16_rne(EXP2F(C2)) << 16);
  const unsigned kT = key15(bf16_rne(fmaf(p2t, i2, fmaf(1.0f, i1, bb))));
  const unsigned mmA = kT * 0x10001u;
  const unsigned mmB = (kT + 1u) * 0x10001u;
  unsigned cge = 0, cgt = 0;
#pragma unroll
  for (int j = 0; j < 16; ++j) {
    cge += ((kg[j] - mmA) >> 15) & 0x10001u;
    cgt += ((kg[j] - mmB) >> 15) & 0x10001u;
  }
  unsigned comb = ((cge & 0xFFFFu) + (cge >> 16)) |
                  (((cgt & 0xFFFFu) + (cgt >> 16)) << 16);
#pragma unroll
  for (int d = 1; d < 64; d <<= 1) comb += (unsigned)__shfl_xor((int)comb, d);
  const unsigned nge = comb & 0xFFFFu, ngt = comb >> 16;
  unsigned thr = kT;
  if (!(nge >= KTOP && ngt < KTOP)) {
    unsigned mn = 0x7FFFu, mx = 0u;
#pragma unroll
    for (int j = 0; j < 16; ++j) {
      const unsigned k15 = kg[j] & 0x7FFF7FFFu;
      mn = min(mn, min(k15 & 0xFFFFu, k15 >> 16));
      mx = max(mx, max(k15 & 0xFFFFu, k15 >> 16));
    }
#pragma unroll
    for (int d = 1; d < 64; d <<= 1) {
      mn = min(mn, (unsigned)__shfl_xor((int)mn, d));
      mx = max(mx, (unsigned)__shfl_xor((int)mx, d));
    }
    unsigned lo2, hi2;
    if (nge < KTOP) { lo2 = mn; hi2 = kT - 1u; } else { lo2 = kT + 1u; hi2 = mx; }
#pragma unroll 1
    for (int it = 0; it < 15; ++it) {
      if (lo2 >= hi2) break;
      const unsigned mid = (lo2 + hi2 + 1u) >> 1;
      const unsigned mm = mid * 0x10001u;
      unsigned c0 = 0;
#pragma unroll
      for (int j = 0; j < 16; ++j) c0 += ((kg[j] - mm) >> 15) & 0x10001u;
      unsigned cnt = (c0 & 0xFFFFu) + (c0 >> 16);
#pragma unroll
      for (int d = 1; d < 64; d <<= 1) cnt += (unsigned)__shfl_xor((int)cnt, d);
      if (cnt >= KTOP) lo2 = mid; else hi2 = mid - 1u;
    }
    thr = lo2;
  }

  // ---- mask (folded into pk) + poly-exp sum ----
  const unsigned lolo = thr * 0x10001u;
  float ssum = 0.f;
#pragma unroll
  for (int j = 0; j < 16; ++j) {
    const unsigned ge = kg[j] - lolo;
    const unsigned msk = ((ge & 0x8000u) ? 0xFFFFu : 0u) |
                         ((ge & 0x80000000u) ? 0xFFFF0000u : 0u);
    pk[j] &= msk;
    const float aA = __uint_as_float(pk[j] << 16);
    const float aB = __uint_as_float(pk[j] & 0xFFFF0000u);
    float eA = fmaf(aA, fmaf(aA, fmaf(aA, 0.166666667f, 0.5f), 1.f), 1.f);
    float eB = fmaf(aB, fmaf(aB, fmaf(aB, 0.166666667f, 0.5f), 1.f), 1.f);
    if (__ballot(fmaxf(__builtin_fabsf(aA), __builtin_fabsf(aB)) > 0.25f)) {
      eA = EXP2F(aA * LOG2E);
      eB = EXP2F(aB * LOG2E);
    }
    ssum += eA + eB;
  }
#pragma unroll
  for (int d = 1; d < 64; d <<= 1) ssum += __shfl_xor(ssum, d);
  const float inv = 1.f / ssum;

  // ---- store: recompute poly from masked pk, float4 coalesced ----
  float* op = out + ((size_t)(b * N_ + n0 + r)) * N_;
#pragma unroll
  for (int k = 0; k < 8; ++k) {
    float e4[4];
#pragma unroll
    for (int h = 0; h < 2; ++h) {
      const unsigned pj = pk[2 * k + h];
      const float aA = __uint_as_float(pj << 16);
      const float aB = __uint_as_float(pj & 0xFFFF0000u);
      float eA = fmaf(aA, fmaf(aA, fmaf(aA, 0.166666667f, 0.5f), 1.f), 1.f);
      float eB = fmaf(aB, fmaf(aB, fmaf(aB, 0.166666667f, 0.5f), 1.f), 1.f);
      if (__ballot(fmaxf(__builtin_fabsf(aA), __builtin_fabsf(aB)) > 0.25f)) {
        eA = EXP2F(aA * LOG2E);
        eB = EXP2F(aB * LOG2E);
      }
      e4[2 * h] = eA; e4[2 * h + 1] = eB;
    }
    float4 o;
    o.x = e4[0] * inv; o.y = e4[1] * inv; o.z = e4[2] * inv; o.w = e4[3] * inv;
    *(float4*)(op + 4 * lane + 256 * k) = o;
  }
}

extern "C" void kernel_launch(void* const* d_in, const int* in_sizes, int n_in,
                              void* d_out, int out_size, void* d_ws, size_t ws_size,
                              hipStream_t stream) {
  const float* x   = (const float*)d_in[0];
  const float* mem = (const float*)d_in[1];
  const float* fcw = (const float*)d_in[2];
  const float* fcb = (const float*)d_in[3];
  float* out = (float*)d_out;
  unsigned short* xsH  = (unsigned short*)d_ws;             // 2 MB
  unsigned short* xsL  = xsH + (size_t)B_ * N_ * C_;        // 2 MB
  unsigned short* memT = xsL + (size_t)B_ * N_ * C_;        // 128 KB

  dim3 g1(N_ / 64, B_);
  prep_kernel<<<g1, 256, 0, stream>>>(x, mem, xsH, xsL, memT);
  dim3 g2(N_ / 8, B_);
  adj_kernel<<<g2, 512, 0, stream>>>(xsH, xsL, memT, fcw, fcb, out);
}

// Round 12
// 133.346 us; speedup vs baseline: 1.7081x; 1.2120x over previous
//
#include <hip/hip_runtime.h>
#include <hip/hip_bf16.h>
#include <cstdint>
#include <cstddef>

#define B_ 16
#define N_ 2048
#define L_ 12
#define C_ 32
#define KTOP 1638
#define SCALE 0.17677669529663687f   // 1/sqrt(32)
#define LOG2E 1.44269504088896f

typedef __attribute__((ext_vector_type(8))) short short8v;
typedef __attribute__((ext_vector_type(4))) float f32x4;

#if __has_builtin(__builtin_amdgcn_exp2f)
#define EXP2F(x) __builtin_amdgcn_exp2f(x)
#else
#define EXP2F(x) exp2f(x)
#endif

__device__ __forceinline__ unsigned short bf16_rne(float v) {
  unsigned u = __float_as_uint(v);
  u += 0x7FFFu + ((u >> 16) & 1u);
  return (unsigned short)(u >> 16);
}
__device__ __forceinline__ unsigned key15(unsigned short b16) {
  const unsigned s = b16 >> 15;
  return ((((unsigned)b16) ^ 0x8000u ^ (s * 0x7FFFu)) >> 1) & 0x7FFFu;
}
// exp(x) quartic for x in [0, 0.72]: err <= 1.6e-3 absolute (x^5/120)
__device__ __forceinline__ float exp_poly4(float x) {
  return fmaf(x, fmaf(x, fmaf(x, fmaf(x, 0.041666667f, 0.166666667f), 0.5f), 1.f), 1.f);
}

// Kernel 1: xsum split into bf16 hi/lo, layout [b][n][c]; blocks with b==0
// also convert mem (f32 [c][m]) -> bf16 memT [m][c] (batch-invariant).
__global__ __launch_bounds__(256) void prep_kernel(const float* __restrict__ x,
                                                   const float* __restrict__ mem,
                                                   unsigned short* __restrict__ xsH,
                                                   unsigned short* __restrict__ xsL,
                                                   unsigned short* __restrict__ memT) {
  const int b = blockIdx.y, n0 = blockIdx.x * 64;
  const int c = threadIdx.x & 31, nr = threadIdx.x >> 5;
#pragma unroll
  for (int i = 0; i < 8; ++i) {
    const int n = n0 + i * 8 + nr;
    const float* px = x + ((size_t)(b * N_ + n) * L_) * C_ + c;
    float s = 0.f;
#pragma unroll
    for (int l = 0; l < L_; ++l) s += px[l * C_];
    const unsigned short h = bf16_rne(s);
    const float hf = __uint_as_float((unsigned)h << 16);
    const unsigned short lo = bf16_rne(s - hf);
    const size_t o = (size_t)(b * N_ + n) * C_ + c;
    xsH[o] = h;
    xsL[o] = lo;
  }
  if (b == 0) {
#pragma unroll
    for (int i = 0; i < 8; ++i) {
      const int idx = i * 256 + threadIdx.x;
      const int ml = idx >> 5, cc = idx & 31;
      memT[(size_t)(n0 + ml) * C_ + cc] = bf16_rne(mem[(size_t)cc * N_ + n0 + ml]);
    }
  }
}

// Kernel 2: R8 skeleton — one block = 8 rows, 512 threads (8 waves), u32 pbuf.
// Phase A: MFMA 16x16x32, permuted A-row padding, max-free softmaxes,
// p1/p2 cvt_pk'd to pbuf (64 KB).
// Phase B (NEW): f32-native fused pass — adj in f32, tie-anchor T bit-exact,
// counts + masked quartic-exp + bf16-packed exp regs in ONE pass; fast path
// self-verified by counts; R8 bf16-key binary search as rare fallback.
__global__ __launch_bounds__(512, 4) void adj_kernel(
    const unsigned short* __restrict__ xsH, const unsigned short* __restrict__ xsL,
    const unsigned short* __restrict__ memT, const float* __restrict__ fc_w,
    const float* __restrict__ fc_b, float* __restrict__ out) {
  __shared__ unsigned pbuf[8][2049];      // +1 pad
  __shared__ float red1[8][8], red2[8][8];

  const int tid = threadIdx.x, wid = tid >> 6, lane = tid & 63;
  const int l15 = lane & 15, g = lane >> 4;
  const int b = blockIdx.y, n0 = blockIdx.x * 8;

  // Permuted A rows: lane group g's C components {0,1} are logical rows
  // {rbase, rbase+1}, rbase = {0,4,2,6}[g].
  const int fr = (l15 < 8) ? l15 : ((l15 - 6) & 7);
  const int rbase = (g & 1) * 4 + (g & 2);
  const int g8 = g * 8;
  const size_t arow = (size_t)(b * N_ + n0 + fr) * C_ + g8;
  const short8v hiA = *(const short8v*)(xsH + arow);
  const short8v loFA = *(const short8v*)(xsL + arow);

  const f32x4 zero = {0.f, 0.f, 0.f, 0.f};
  const float K = SCALE * LOG2E;
  const float C2 = -80.f * LOG2E;
  const int mbase = wid * 256 + l15;
  const size_t bcol = (size_t)b * N_ * C_ + (size_t)mbase * C_ + g8;
  const unsigned short* pH = xsH + bcol;
  const unsigned short* pL = xsL + bcol;
  const unsigned short* pM = memT + (size_t)mbase * C_ + g8;
  unsigned* pw = &pbuf[rbase][mbase];

  float s1[2] = {0.f, 0.f}, s2[2] = {0.f, 0.f};

#pragma unroll
  for (int t = 0; t < 16; ++t) {
    const short8v hiB = *(const short8v*)(pH + t * (16 * C_));
    const short8v loB = *(const short8v*)(pL + t * (16 * C_));
    const short8v mB  = *(const short8v*)(pM + t * (16 * C_));

    f32x4 acc1 = __builtin_amdgcn_mfma_f32_16x16x32_bf16(hiA, mB, zero, 0, 0, 0);
    f32x4 acc2 = __builtin_amdgcn_mfma_f32_16x16x32_bf16(hiA, hiB, zero, 0, 0, 0);
    acc2 = __builtin_amdgcn_mfma_f32_16x16x32_bf16(hiA, loB, acc2, 0, 0, 0);
    acc2 = __builtin_amdgcn_mfma_f32_16x16x32_bf16(loFA, hiB, acc2, 0, 0, 0);

#pragma unroll
    for (int s = 0; s < 2; ++s) {
      const float p1 = EXP2F(fmaxf(acc1[s], 0.f) * K);
      const float p2 = EXP2F(fminf(fmaf(fmaxf(acc2[s], 0.f), K, C2), 127.f));
      s1[s] += p1; s2[s] += p2;
      union { __hip_bfloat162 h2; unsigned u; } pk;
      pk.h2 = __float22bfloat162_rn(float2{p1, p2});
      pw[s * 2049 + t * 16] = pk.u;
    }
  }

#pragma unroll
  for (int d = 1; d < 16; d <<= 1) {
#pragma unroll
    for (int s = 0; s < 2; ++s) {
      s1[s] += __shfl_xor(s1[s], d);
      s2[s] += __shfl_xor(s2[s], d);
    }
  }
  if (l15 == 0) {
#pragma unroll
    for (int s = 0; s < 2; ++s) {
      red1[wid][rbase + s] = s1[s];
      red2[wid][rbase + s] = s2[s];
    }
  }
  __syncthreads();

  // ---- Phase B: wave wid owns row wid; lane owns cols {4*lane+256k} ----
  const int r = wid;
  float S1 = 0.f, S2 = 0.f;
#pragma unroll
  for (int w = 0; w < 8; ++w) { S1 += red1[w][r]; S2 += red2[w][r]; }
  const float w0 = fc_w[0], w1 = fc_w[1], bb = fc_b[0];
  const float i1 = w0 / S1, i2 = w1 / S2;
  const unsigned* prow = &pbuf[0][0] + r * 2049;

  // Tie value T, bit-exact vs the per-element adj computation below.
  const float p2t = __uint_as_float((unsigned)bf16_rne(EXP2F(C2)) << 16);
  const float T = fmaf(p2t, i2, fmaf(1.0f, i1, bb));

  // Fused pass: adj (f32), counts vs T, masked quartic exp, bf16-pack.
  unsigned exb[16];          // packed bf16 exp pairs
  float ssum = 0.f;
  unsigned cge = 0, cgt = 0;
#pragma unroll
  for (int k = 0; k < 8; ++k) {
    const uint4 q = *(const uint4*)&prow[4 * lane + 256 * k];
    const unsigned qq[4] = {q.x, q.y, q.z, q.w};
    float e4[4];
#pragma unroll
    for (int c4 = 0; c4 < 4; ++c4) {
      const float p1 = __uint_as_float(qq[c4] << 16);
      const float p2 = __uint_as_float(qq[c4] & 0xFFFF0000u);
      const float adj = fmaf(p2, i2, fmaf(p1, i1, bb));
      cge += (adj >= T) ? 1u : 0u;
      cgt += (adj >  T) ? 1u : 0u;
      const float am = (adj >= T) ? adj : 0.f;
      const float e = exp_poly4(am);
      e4[c4] = e;
      ssum += e;
    }
    union { __hip_bfloat162 h2; unsigned u; } pa, pb2;
    pa.h2  = __float22bfloat162_rn(float2{e4[0], e4[1]});
    pb2.h2 = __float22bfloat162_rn(float2{e4[2], e4[3]});
    exb[2 * k] = pa.u; exb[2 * k + 1] = pb2.u;
  }
  unsigned comb = cge | (cgt << 16);
#pragma unroll
  for (int d = 1; d < 64; d <<= 1) {
    comb += (unsigned)__shfl_xor((int)comb, d);
    ssum += __shfl_xor(ssum, d);
  }
  const unsigned CGE = comb & 0xFFFFu, CGT = comb >> 16;

  float* op = out + ((size_t)(b * N_ + n0 + r)) * N_;

  if (CGE >= KTOP && CGT < KTOP) {
    // ---- fast path (expected always): threshold is T, sum is ssum ----
    const float inv = 1.f / ssum;
#pragma unroll
    for (int k = 0; k < 8; ++k) {
      float4 o;
      o.x = __uint_as_float(exb[2 * k] << 16) * inv;
      o.y = __uint_as_float(exb[2 * k] & 0xFFFF0000u) * inv;
      o.z = __uint_as_float(exb[2 * k + 1] << 16) * inv;
      o.w = __uint_as_float(exb[2 * k + 1] & 0xFFFF0000u) * inv;
      *(float4*)(op + 4 * lane + 256 * k) = o;
    }
  } else {
    // ---- rare fallback: R8-style bf16-key binary search, then store ----
    unsigned pk2[16], kg[16];
#pragma unroll
    for (int k = 0; k < 8; ++k) {
      const uint4 q = *(const uint4*)&prow[4 * lane + 256 * k];
      const unsigned qq[4] = {q.x, q.y, q.z, q.w};
      float a4[4];
#pragma unroll
      for (int c4 = 0; c4 < 4; ++c4) {
        const float p1 = __uint_as_float(qq[c4] << 16);
        const float p2 = __uint_as_float(qq[c4] & 0xFFFF0000u);
        a4[c4] = fmaf(p2, i2, fmaf(p1, i1, bb));
      }
      union { __hip_bfloat162 h2; unsigned u; } cA, cB;
      cA.h2 = __float22bfloat162_rn(float2{a4[0], a4[1]});
      cB.h2 = __float22bfloat162_rn(float2{a4[2], a4[3]});
      pk2[2 * k] = cA.u; pk2[2 * k + 1] = cB.u;
      unsigned sgn = (cA.u >> 15) & 0x00010001u;
      unsigned srt = cA.u ^ 0x80008000u ^ (sgn * 0x7FFFu);
      kg[2 * k] = ((srt >> 1) & 0x7FFF7FFFu) | 0x80008000u;
      sgn = (pk2[2 * k + 1] >> 15) & 0x00010001u;
      srt = pk2[2 * k + 1] ^ 0x80008000u ^ (sgn * 0x7FFFu);
      kg[2 * k + 1] = ((srt >> 1) & 0x7FFF7FFFu) | 0x80008000u;
    }
    unsigned mn = 0x7FFFu, mx = 0u;
#pragma unroll
    for (int j = 0; j < 16; ++j) {
      const unsigned k15 = kg[j] & 0x7FFF7FFFu;
      mn = min(mn, min(k15 & 0xFFFFu, k15 >> 16));
      mx = max(mx, max(k15 & 0xFFFFu, k15 >> 16));
    }
#pragma unroll
    for (int d = 1; d < 64; d <<= 1) {
      mn = min(mn, (unsigned)__shfl_xor((int)mn, d));
      mx = max(mx, (unsigned)__shfl_xor((int)mx, d));
    }
    unsigned lo2 = mn, hi2 = mx;
#pragma unroll 1
    for (int it = 0; it < 15; ++it) {
      if (lo2 >= hi2) break;
      const unsigned mid = (lo2 + hi2 + 1u) >> 1;
      const unsigned mm = mid * 0x10001u;
      unsigned c0 = 0;
#pragma unroll
      for (int j = 0; j < 16; ++j) c0 += ((kg[j] - mm) >> 15) & 0x10001u;
      unsigned cnt = (c0 & 0xFFFFu) + (c0 >> 16);
#pragma unroll
      for (int d = 1; d < 64; d <<= 1) cnt += (unsigned)__shfl_xor((int)cnt, d);
      if (cnt >= KTOP) lo2 = mid; else hi2 = mid - 1u;
    }
    const unsigned lolo = lo2 * 0x10001u;
    float s2sum = 0.f;
    float exf[32];
#pragma unroll
    for (int j = 0; j < 16; ++j) {
      const unsigned ge = kg[j] - lolo;
      const float aA = (ge & 0x8000u) ? __uint_as_float(pk2[j] << 16) : 0.f;
      const float aB = (ge & 0x80000000u) ? __uint_as_float(pk2[j] & 0xFFFF0000u) : 0.f;
      const float eA = EXP2F(aA * LOG2E);
      const float eB = EXP2F(aB * LOG2E);
      exf[2 * j] = eA; exf[2 * j + 1] = eB;
      s2sum += eA + eB;
    }
#pragma unroll
    for (int d = 1; d < 64; d <<= 1) s2sum += __shfl_xor(s2sum, d);
    const float inv = 1.f / s2sum;
#pragma unroll
    for (int k = 0; k < 8; ++k) {
      float4 o;
      o.x = exf[4 * k + 0] * inv; o.y = exf[4 * k + 1] * inv;
      o.z = exf[4 * k + 2] * inv; o.w = exf[4 * k + 3] * inv;
      *(float4*)(op + 4 * lane + 256 * k) = o;
    }
  }
}

extern "C" void kernel_launch(void* const* d_in, const int* in_sizes, int n_in,
                              void* d_out, int out_size, void* d_ws, size_t ws_size,
                              hipStream_t stream) {
  const float* x   = (const float*)d_in[0];
  const float* mem = (const float*)d_in[1];
  const float* fcw = (const float*)d_in[2];
  const float* fcb = (const float*)d_in[3];
  float* out = (float*)d_out;
  unsigned short* xsH  = (unsigned short*)d_ws;             // 2 MB
  unsigned short* xsL  = xsH + (size_t)B_ * N_ * C_;        // 2 MB
  unsigned short* memT = xsL + (size_t)B_ * N_ * C_;        // 128 KB

  dim3 g1(N_ / 64, B_);
  prep_kernel<<<g1, 256, 0, stream>>>(x, mem, xsH, xsL, memT);
  dim3 g2(N_ / 8, B_);
  adj_kernel<<<g2, 512, 0, stream>>>(xsH, xsL, memT, fcw, fcb, out);
}